// Round 1
// baseline (508.557 us; speedup 1.0000x reference)
//
#include <hip/hip_runtime.h>

#define B_ 64
#define C_ 768
#define S_ 8
#define H_ 28
#define W_ 28
#define HW_ (H_*W_)           // 784
#define CPB_ 96               // channels per conv block
#define NCHUNK_ (C_/CPB_)     // 8
#define CT_ 64                // channels per einsum block
#define NCT_ (C_/CT_)         // 12
#define CH_ 196               // hw chunk for einsum
#define NCH_ (HW_/CH_)        // 4
#define XPAD_ 197             // LDS row stride (dwords): 197%32=5, conflict-free

// ---------------- K1: partial conv, atomically accumulated into d_ws ----------
// grid (196, 8), block 256. thread <-> one output pixel (b,h,w); 8 s-accumulators.
__global__ __launch_bounds__(256) void conv_partial(
    const float* __restrict__ x, const float* __restrict__ w,
    float* __restrict__ acc_ws)
{
  const int tid  = threadIdx.x;
  const int flat = blockIdx.x * 256 + tid;      // [0, 50176)
  const int b    = flat / HW_;
  const int hw   = flat - b * HW_;
  const int h    = hw / W_;
  const int wI   = hw - h * W_;
  const int c0   = blockIdx.y * CPB_;

  // 9 taps: clamped offset + 0/1 mask (uniform code, no divergence)
  int   off[9];
  float msk[9];
  #pragma unroll
  for (int dy = -1; dy <= 1; ++dy) {
    #pragma unroll
    for (int dx = -1; dx <= 1; ++dx) {
      int t  = (dy + 1) * 3 + (dx + 1);
      int hh = h + dy, ww = wI + dx;
      bool v = (hh >= 0) & (hh < H_) & (ww >= 0) & (ww < W_);
      int hc = min(max(hh, 0), H_ - 1);
      int wc = min(max(ww, 0), W_ - 1);
      off[t] = hc * W_ + wc;
      msk[t] = v ? 1.0f : 0.0f;
    }
  }

  float acc[S_];
  #pragma unroll
  for (int s = 0; s < S_; ++s) acc[s] = 0.0f;

  const float* xb = x + (size_t)(b * C_ + c0) * HW_;

  #pragma unroll 2
  for (int cl = 0; cl < CPB_; ++cl) {
    const float* xc = xb + cl * HW_;
    float xv[9];
    #pragma unroll
    for (int t = 0; t < 9; ++t) xv[t] = xc[off[t]] * msk[t];

    // wave-uniform weight address -> scalar loads (SGPR operand in FMA)
    const float* wp = w + (size_t)(c0 + cl) * 9;
    #pragma unroll
    for (int s = 0; s < S_; ++s) {
      float a = acc[s];
      #pragma unroll
      for (int t = 0; t < 9; ++t)
        a = fmaf(xv[t], wp[(size_t)s * (C_ * 9) + t], a);
      acc[s] = a;
    }
  }

  float* dst = acc_ws + (size_t)(b * S_) * HW_ + hw;
  #pragma unroll
  for (int s = 0; s < S_; ++s) atomicAdd(dst + s * HW_, acc[s]);
}

// ---------------- K2: mask = acc + bias (write), learned = x.mask/HW ----------
// grid (12, 64), block 256. thread = (q=tid>>6, cl=tid&63).
__global__ __launch_bounds__(256) void einsum_k(
    const float* __restrict__ x, const float* __restrict__ acc_ws,
    const float* __restrict__ bias, float* __restrict__ out)
{
  __shared__ float xs[CT_ * XPAD_];   // 50432 B
  __shared__ float ms[S_ * CH_];      // 6272 B
  __shared__ float red[256 * S_];     // 8192 B  (total 64896 <= 64KB)

  const int tid = threadIdx.x;
  const int cx  = blockIdx.x;         // channel tile 0..11
  const int b   = blockIdx.y;         // batch
  const int c0  = cx * CT_;
  const int q   = tid >> 6;           // hw quarter 0..3
  const int cl  = tid & 63;           // channel within tile

  float pacc[S_];
  #pragma unroll
  for (int s = 0; s < S_; ++s) pacc[s] = 0.0f;

  float* outL = out;                          // [B,C,S]
  float* outM = out + (size_t)B_ * C_ * S_;   // [B,S,H,W]

  for (int ch = 0; ch < NCH_; ++ch) {
    __syncthreads();
    // mask chunk (+bias) into LDS
    for (int i = tid; i < S_ * CH_; i += 256) {
      int s = i / CH_, j = i - s * CH_;
      ms[i] = acc_ws[(size_t)(b * S_ + s) * HW_ + ch * CH_ + j] + bias[s];
    }
    // x chunk into LDS (coalesced global, pad-197 rows)
    for (int i = tid; i < CT_ * CH_; i += 256) {
      int c = i / CH_, j = i - c * CH_;
      xs[c * XPAD_ + j] = x[(size_t)(b * C_ + c0 + c) * HW_ + ch * CH_ + j];
    }
    __syncthreads();

    if (cx == 0) {  // one tile per b emits region_mask
      for (int i = tid; i < S_ * CH_; i += 256) {
        int s = i / CH_, j = i - s * CH_;
        outM[(size_t)(b * S_ + s) * HW_ + ch * CH_ + j] = ms[i];
      }
    }

    // compute: lane<->channel (conflict-free), mask broadcast across wave
    const float* xrow = xs + cl * XPAD_ + q * 49;
    #pragma unroll 7
    for (int j = 0; j < 49; ++j) {
      float xv = xrow[j];
      #pragma unroll
      for (int s = 0; s < S_; ++s)
        pacc[s] = fmaf(xv, ms[s * CH_ + q * 49 + j], pacc[s]);
    }
  }

  __syncthreads();
  #pragma unroll
  for (int s = 0; s < S_; ++s) red[tid * S_ + s] = pacc[s];
  __syncthreads();

  for (int i = tid; i < CT_ * S_; i += 256) {
    int c = i >> 3, s = i & 7;
    float v = red[(0 * 64 + c) * S_ + s] + red[(1 * 64 + c) * S_ + s]
            + red[(2 * 64 + c) * S_ + s] + red[(3 * 64 + c) * S_ + s];
    outL[((size_t)(b * C_) + c0 + c) * S_ + s] = v * (1.0f / HW_);
  }
}

extern "C" void kernel_launch(void* const* d_in, const int* in_sizes, int n_in,
                              void* d_out, int out_size, void* d_ws, size_t ws_size,
                              hipStream_t stream) {
  const float* x    = (const float*)d_in[0];
  const float* w    = (const float*)d_in[1];
  const float* bias = (const float*)d_in[2];
  float* out = (float*)d_out;
  float* acc = (float*)d_ws;   // [B,S,HW] fp32 accumulator = 1.6 MB

  hipMemsetAsync(acc, 0, (size_t)B_ * S_ * HW_ * sizeof(float), stream);
  conv_partial<<<dim3(196, NCHUNK_), 256, 0, stream>>>(x, w, acc);
  einsum_k<<<dim3(NCT_, B_), 256, 0, stream>>>(x, acc, bias, out);
}

// Round 3
// 445.168 us; speedup vs baseline: 1.1424x; 1.1424x over previous
//
#include <hip/hip_runtime.h>

#define B_ 64
#define C_ 768
#define S_ 8
#define H_ 28
#define W_ 28
#define HW_ 784
#define FR_ 900               // 30x30 zero-padded frame
#define CPB_ 96               // channels per conv block
#define NCHUNK_ 8             // C / CPB
#define CSTEP_ 8              // channels staged per step
#define NSTEP_ (CPB_/CSTEP_)  // 12
#define CONVT_ 896            // conv threads: 14 waves x 56 px = 784
#define CT_ 64                // einsum channel tile
#define NCT_ 12
#define CH_ 196               // einsum hw chunk
#define NCH_ 4
#define XPAD_ 197             // LDS row stride: 197%32=5 -> conflict-free

// ---------------- K1: conv partials, LDS-staged padded frames ----------------
__global__ __launch_bounds__(CONVT_) void conv_k(
    const float* __restrict__ x, const float* __restrict__ w,
    float* __restrict__ mask_acc)
{
  __shared__ float xb[2 * CSTEP_ * FR_];   // 57600 B
  const int tid  = threadIdx.x;
  const int b    = blockIdx.x;
  const int c0   = blockIdx.y * CPB_;
  const int wv   = tid >> 6;
  const int lane = tid & 63;
  const int p    = wv * 56 + lane;         // pixel, valid if lane<56
  const bool act = lane < 56;
  const int h    = p / 28;
  const int wI   = p - h * 28;
  const int pb   = (h + 1) * 30 + (wI + 1);

  // zero LDS once: borders stay zero forever
  for (int i = tid; i < 2 * CSTEP_ * FR_; i += CONVT_) xb[i] = 0.0f;
  __syncthreads();

  const float* xbase = x + ((size_t)b * C_ + c0) * HW_;

  // prologue: stage step 0 into buffer 0 (interior cells only)
  {
    const float4* src = (const float4*)xbase;
    #pragma unroll
    for (int r = 0; r < 2; ++r) {
      int i4 = tid + r * CONVT_;
      if (i4 < CSTEP_ * HW_ / 4) {
        float4 v = src[i4];
        int cl = i4 / 196, rr = i4 - cl * 196;
        int hw0 = rr * 4, hh = hw0 / 28, ww = hw0 - hh * 28;
        float* d = &xb[cl * FR_ + (hh + 1) * 30 + (ww + 1)];
        d[0] = v.x; d[1] = v.y; d[2] = v.z; d[3] = v.w;
      }
    }
  }

  float acc[S_];
  #pragma unroll
  for (int s = 0; s < S_; ++s) acc[s] = 0.0f;

  for (int k = 0; k < NSTEP_; ++k) {
    const int cur = k & 1;
    float4 g[2];
    // issue next step's global loads early (latency hides under compute)
    const bool pre = (k + 1 < NSTEP_);
    if (pre) {
      const float4* src = (const float4*)(xbase + (size_t)(k + 1) * CSTEP_ * HW_);
      #pragma unroll
      for (int r = 0; r < 2; ++r) {
        int i4 = tid + r * CONVT_;
        if (i4 < CSTEP_ * HW_ / 4) g[r] = src[i4];
      }
    }
    __syncthreads();   // buf[cur] fully written & everyone done with buf[cur^1]

    const float* fb = &xb[cur * CSTEP_ * FR_];
    if (act) {
      #pragma unroll
      for (int cl = 0; cl < CSTEP_; ++cl) {
        const float* f = fb + cl * FR_ + pb;
        float xv[9];
        xv[0] = f[-31]; xv[1] = f[-30]; xv[2] = f[-29];
        xv[3] = f[-1];  xv[4] = f[0];   xv[5] = f[1];
        xv[6] = f[29];  xv[7] = f[30];  xv[8] = f[31];
        const float* wp = w + (size_t)(c0 + k * CSTEP_ + cl) * 9;  // uniform -> SGPR
        #pragma unroll
        for (int s = 0; s < S_; ++s) {
          float a = acc[s];
          #pragma unroll
          for (int t = 0; t < 9; ++t)
            a = fmaf(xv[t], wp[(size_t)s * (C_ * 9) + t], a);
          acc[s] = a;
        }
      }
    }

    if (pre) {  // write prefetched regs into the other buffer
      float* fb2 = &xb[(cur ^ 1) * CSTEP_ * FR_];
      #pragma unroll
      for (int r = 0; r < 2; ++r) {
        int i4 = tid + r * CONVT_;
        if (i4 < CSTEP_ * HW_ / 4) {
          int cl = i4 / 196, rr = i4 - cl * 196;
          int hw0 = rr * 4, hh = hw0 / 28, ww = hw0 - hh * 28;
          float* d = &fb2[cl * FR_ + (hh + 1) * 30 + (ww + 1)];
          d[0] = g[r].x; d[1] = g[r].y; d[2] = g[r].z; d[3] = g[r].w;
        }
      }
    }
  }

  if (act) {
    float* dst = mask_acc + (size_t)b * S_ * HW_ + p;
    #pragma unroll
    for (int s = 0; s < S_; ++s) atomicAdd(dst + s * HW_, acc[s]);
  }
}

// ---------------- K2: region_mask output = mask_acc + bias -------------------
__global__ __launch_bounds__(256) void mask_bias_k(
    const float* __restrict__ mask_acc, const float* __restrict__ bias,
    float* __restrict__ outM)
{
  int i4 = blockIdx.x * 256 + threadIdx.x;        // < 100352
  float4 v = ((const float4*)mask_acc)[i4];
  int s = (i4 / 196) & 7;                         // 196 float4 per (b,s) row
  float bv = bias[s];
  v.x += bv; v.y += bv; v.z += bv; v.w += bv;
  ((float4*)outM)[i4] = v;
}

// ---------------- K3: learned = (x . m_raw + bias * sum(x)) / HW -------------
__global__ __launch_bounds__(256) void einsum_k(
    const float* __restrict__ x, const float* __restrict__ mask_acc,
    const float* __restrict__ bias, float* __restrict__ out)
{
  __shared__ float xs[CT_ * XPAD_];   // 50432 B (reused as reduction buffer)
  const int tid = threadIdx.x;
  const int cx  = blockIdx.x;
  const int b   = blockIdx.y;
  const int c0  = cx * CT_;
  const int q   = __builtin_amdgcn_readfirstlane(tid >> 6);  // wave id, force SGPR
  const int cl  = tid & 63;

  float pacc[S_];
  #pragma unroll
  for (int s = 0; s < S_; ++s) pacc[s] = 0.0f;
  float sumx = 0.0f;

  const float*  xbase = x + ((size_t)b * C_ + c0) * HW_;
  const float4* src4  = (const float4*)xbase;
  const float*  mrow  = mask_acc + (size_t)b * S_ * HW_;

  for (int ch = 0; ch < NCH_; ++ch) {
    __syncthreads();   // previous chunk's compute done before overwrite
    for (int r = 0; r < 13; ++r) {
      int i4 = tid + r * 256;
      if (i4 < CT_ * CH_ / 4) {
        int c = i4 / 49, j4 = i4 - c * 49;
        float4 v = src4[c * (HW_ / 4) + ch * 49 + j4];
        float* d = &xs[c * XPAD_ + j4 * 4];
        d[0] = v.x; d[1] = v.y; d[2] = v.z; d[3] = v.w;
      }
    }
    __syncthreads();

    const float* mq   = mrow + ch * CH_ + q * 49;   // uniform -> s_load
    const float* xrow = &xs[cl * XPAD_ + q * 49];
    #pragma unroll 7
    for (int j = 0; j < 49; ++j) {
      float xv = xrow[j];       // ds_read, stride-197 -> conflict-free
      sumx += xv;
      #pragma unroll
      for (int s = 0; s < S_; ++s)
        pacc[s] = fmaf(xv, mq[(size_t)s * HW_ + j], pacc[s]);  // SGPR mask operand
    }
  }

  // reduce the 4 hw-quarters (waves) through LDS (reuse xs)
  __syncthreads();
  float* red = xs;   // 256 * 9 floats
  #pragma unroll
  for (int s = 0; s < S_; ++s) red[tid * 9 + s] = pacc[s];
  red[tid * 9 + 8] = sumx;
  __syncthreads();

  for (int i = tid; i < CT_ * S_; i += 256) {
    int c = i >> 3, s = i & 7;
    float vs = 0.0f, vx = 0.0f;
    #pragma unroll
    for (int qq = 0; qq < 4; ++qq) {
      vs += red[(qq * 64 + c) * 9 + s];
      vx += red[(qq * 64 + c) * 9 + 8];
    }
    out[((size_t)b * C_ + c0 + c) * S_ + s] = (vs + bias[s] * vx) * (1.0f / HW_);
  }
}

extern "C" void kernel_launch(void* const* d_in, const int* in_sizes, int n_in,
                              void* d_out, int out_size, void* d_ws, size_t ws_size,
                              hipStream_t stream) {
  const float* x    = (const float*)d_in[0];
  const float* w    = (const float*)d_in[1];
  const float* bias = (const float*)d_in[2];
  float* out  = (float*)d_out;
  float* outM = out + (size_t)B_ * C_ * S_;
  float* acc  = (float*)d_ws;   // [B,S,HW] fp32 accumulator = 1.6 MB

  hipMemsetAsync(acc, 0, (size_t)B_ * S_ * HW_ * sizeof(float), stream);
  conv_k<<<dim3(B_, NCHUNK_), CONVT_, 0, stream>>>(x, w, acc);
  mask_bias_k<<<(B_ * S_ * HW_ / 4 + 255) / 256, 256, 0, stream>>>(acc, bias, outM);
  einsum_k<<<dim3(NCT_, B_), 256, 0, stream>>>(x, acc, bias, out);
}

// Round 7
// 373.126 us; speedup vs baseline: 1.3630x; 1.1931x over previous
//
#include <hip/hip_runtime.h>

#define B_ 64
#define C_ 768
#define S_ 8
#define HW_ 784
#define FR_ 900               // 30x30 zero-padded frame
// conv
#define CPB_ 48               // channels per conv block
#define NCHUNK_ 16            // C / CPB
#define CSTEP_ 4              // channels staged per step
#define NSTEP_ 12             // CPB / CSTEP
// einsum
#define EJ_ 112               // hw positions per round
#define NRND_ 7               // 784 / 112
#define XPITCH_ 116           // dword pitch: %32=20 -> uniform b128 start banks

// ---------------- K0: weight transpose wT[c][s*9+t] = w[s][c][t] -------------
__global__ __launch_bounds__(256) void wtrans_k(
    const float* __restrict__ w, float* __restrict__ wT)
{
  int idx = blockIdx.x * 256 + threadIdx.x;     // < 768*72 = 55296
  int c = idx / 72, r = idx - c * 72;
  int s = r / 9,  t = r - s * 9;
  wT[idx] = w[(size_t)s * (C_ * 9) + c * 9 + t];
}

// ---------------- K1: conv partials (quad-pixel threads) ---------------------
// grid (64, 16), block 256. tid<196 -> one 4-pixel quad; all threads stage.
__global__ __launch_bounds__(256, 4) void conv_k(
    const float* __restrict__ x, const float* __restrict__ wT,
    float* __restrict__ mask_acc)
{
  __shared__ float xb[CSTEP_ * FR_];   // 14400 B
  const int tid = threadIdx.x;
  const int b   = blockIdx.x;
  const int c0  = blockIdx.y * CPB_;
  const bool act = tid < 196;
  const int qd  = act ? tid : 0;
  const int h   = qd / 7;
  const int wq  = (qd - h * 7) * 4;
  const int pb  = (h + 1) * 30 + (wq + 1);

  // zero once: borders persist, interior overwritten every step
  for (int i = tid; i < CSTEP_ * FR_; i += 256) xb[i] = 0.0f;

  const float4* src4 = (const float4*)(x + ((size_t)b * C_ + c0) * HW_);

  float acc[4][S_];
  #pragma unroll
  for (int px = 0; px < 4; ++px)
    #pragma unroll
    for (int s = 0; s < S_; ++s) acc[px][s] = 0.0f;

  for (int k = 0; k < NSTEP_; ++k) {
    __syncthreads();                    // zero-init / prev-step reads done
    #pragma unroll
    for (int r = 0; r < 4; ++r) {
      int i4 = tid + r * 256;
      if (i4 < CSTEP_ * HW_ / 4) {      // 784 float4
        float4 v = src4[k * 784 + i4];
        int cl = i4 / 196, rr = i4 - cl * 196;
        int hw0 = rr * 4, hh = hw0 / 28, ww = hw0 - hh * 28;
        float* d = &xb[cl * FR_ + (hh + 1) * 30 + (ww + 1)];
        d[0] = v.x; d[1] = v.y; d[2] = v.z; d[3] = v.w;
      }
    }
    __syncthreads();                    // tile visible

    if (act) {
      #pragma unroll
      for (int cl = 0; cl < CSTEP_; ++cl) {
        const float* f = &xb[cl * FR_ + pb];
        float xv[3][6];                 // 3 tap-rows x 6 columns covers 4 px
        #pragma unroll
        for (int r3 = 0; r3 < 3; ++r3)
          #pragma unroll
          for (int m = 0; m < 6; ++m)
            xv[r3][m] = f[(r3 - 1) * 30 - 1 + m];

        const float4* wrow = (const float4*)(wT + (size_t)(c0 + k * CSTEP_ + cl) * 72);
        float wa[36];
        #pragma unroll
        for (int i = 0; i < 9; ++i) ((float4*)wa)[i] = wrow[i];       // s=0..3
        #pragma unroll
        for (int s = 0; s < 4; ++s)
          #pragma unroll
          for (int px = 0; px < 4; ++px) {
            float a = acc[px][s];
            #pragma unroll
            for (int r3 = 0; r3 < 3; ++r3)
              #pragma unroll
              for (int kx = 0; kx < 3; ++kx)
                a = fmaf(xv[r3][px + kx], wa[s * 9 + r3 * 3 + kx], a);
            acc[px][s] = a;
          }
        #pragma unroll
        for (int i = 0; i < 9; ++i) ((float4*)wa)[i] = wrow[9 + i];   // s=4..7
        #pragma unroll
        for (int s = 0; s < 4; ++s)
          #pragma unroll
          for (int px = 0; px < 4; ++px) {
            float a = acc[px][s + 4];
            #pragma unroll
            for (int r3 = 0; r3 < 3; ++r3)
              #pragma unroll
              for (int kx = 0; kx < 3; ++kx)
                a = fmaf(xv[r3][px + kx], wa[s * 9 + r3 * 3 + kx], a);
            acc[px][s + 4] = a;
          }
      }
    }
  }

  if (act) {
    float* dst = mask_acc + (size_t)b * S_ * HW_ + h * 28 + wq;
    #pragma unroll
    for (int s = 0; s < S_; ++s)
      #pragma unroll
      for (int px = 0; px < 4; ++px)
        atomicAdd(dst + (size_t)s * HW_ + px, acc[px][s]);
  }
}

// ---------------- K2: region_mask output = mask_acc + bias -------------------
__global__ __launch_bounds__(256) void mask_bias_k(
    const float* __restrict__ mask_acc, const float* __restrict__ bias,
    float* __restrict__ outM)
{
  int i4 = blockIdx.x * 256 + threadIdx.x;        // < 100352
  float4 v = ((const float4*)mask_acc)[i4];
  int s = (i4 / 196) & 7;
  float bv = bias[s];
  v.x += bv; v.y += bv; v.z += bv; v.w += bv;
  ((float4*)outM)[i4] = v;
}

// ---------------- K3: learned = (x . m_raw + bias * sum(x)) / HW -------------
// grid (12, 64), block 256. lane<->channel, wave q owns 28 j per round.
__global__ __launch_bounds__(256, 4) void einsum_k(
    const float* __restrict__ x, const float* __restrict__ mask_acc,
    const float* __restrict__ bias, float* __restrict__ out)
{
  __shared__ float xs[64 * XPITCH_];   // 29696 B (reused for reduction)
  const int tid = threadIdx.x;
  const int cx  = blockIdx.x;
  const int b   = blockIdx.y;
  const int c0  = cx * 64;
  const int q   = tid >> 6;            // wave -> j sub-block
  const int cl  = tid & 63;            // channel lane
  const int jq  = q * 28;              // round-local j base

  float acc[S_];
  #pragma unroll
  for (int s = 0; s < S_; ++s) acc[s] = 0.0f;
  float sumx = 0.0f;

  const float4* src4 = (const float4*)(x + ((size_t)b * C_ + c0) * HW_);
  const float*  mrow = mask_acc + (size_t)b * S_ * HW_;

  for (int rnd = 0; rnd < NRND_; ++rnd) {
    __syncthreads();                    // previous round's reads done
    #pragma unroll
    for (int r = 0; r < 7; ++r) {
      int i4 = tid + r * 256;           // exactly 1792 = 7*256
      int c = i4 / 28, j4 = i4 - c * 28;
      float4 v = src4[c * 196 + rnd * 28 + j4];
      *(float4*)&xs[c * XPITCH_ + j4 * 4] = v;
    }
    __syncthreads();

    // 3 groups of 8 j + 1 tail of 4 j  (28 total for this wave)
    #pragma unroll
    for (int g = 0; g < 3; ++g) {
      const int j0 = rnd * EJ_ + jq + g * 8;     // global j, 16B-aligned
      float4 m0[S_], m1[S_];
      #pragma unroll
      for (int s = 0; s < S_; ++s) {
        m0[s] = *(const float4*)(mrow + (size_t)s * HW_ + j0);
        m1[s] = *(const float4*)(mrow + (size_t)s * HW_ + j0 + 4);
      }
      float4 xa = *(const float4*)&xs[cl * XPITCH_ + jq + g * 8];
      float4 xb2 = *(const float4*)&xs[cl * XPITCH_ + jq + g * 8 + 4];
      sumx += xa.x + xa.y + xa.z + xa.w + xb2.x + xb2.y + xb2.z + xb2.w;
      #pragma unroll
      for (int s = 0; s < S_; ++s) {
        float a = acc[s];
        a = fmaf(xa.x, m0[s].x, a); a = fmaf(xa.y, m0[s].y, a);
        a = fmaf(xa.z, m0[s].z, a); a = fmaf(xa.w, m0[s].w, a);
        a = fmaf(xb2.x, m1[s].x, a); a = fmaf(xb2.y, m1[s].y, a);
        a = fmaf(xb2.z, m1[s].z, a); a = fmaf(xb2.w, m1[s].w, a);
        acc[s] = a;
      }
    }
    {   // tail 4 j
      const int j0 = rnd * EJ_ + jq + 24;
      float4 m0[S_];
      #pragma unroll
      for (int s = 0; s < S_; ++s)
        m0[s] = *(const float4*)(mrow + (size_t)s * HW_ + j0);
      float4 xa = *(const float4*)&xs[cl * XPITCH_ + jq + 24];
      sumx += xa.x + xa.y + xa.z + xa.w;
      #pragma unroll
      for (int s = 0; s < S_; ++s) {
        float a = acc[s];
        a = fmaf(xa.x, m0[s].x, a); a = fmaf(xa.y, m0[s].y, a);
        a = fmaf(xa.z, m0[s].z, a); a = fmaf(xa.w, m0[s].w, a);
        acc[s] = a;
      }
    }
  }

  // reduce 4 waves through LDS (reuse xs)
  __syncthreads();
  float* red = xs;                      // 256*9 floats
  #pragma unroll
  for (int s = 0; s < S_; ++s) red[tid * 9 + s] = acc[s];
  red[tid * 9 + 8] = sumx;
  __syncthreads();

  for (int i = tid; i < 64 * S_; i += 256) {
    int c = i >> 3, s = i & 7;
    float vs = 0.0f, vx = 0.0f;
    #pragma unroll
    for (int qq = 0; qq < 4; ++qq) {
      vs += red[(qq * 64 + c) * 9 + s];
      vx += red[(qq * 64 + c) * 9 + 8];
    }
    out[((size_t)b * C_ + c0 + c) * S_ + s] = (vs + bias[s] * vx) * (1.0f / HW_);
  }
}

extern "C" void kernel_launch(void* const* d_in, const int* in_sizes, int n_in,
                              void* d_out, int out_size, void* d_ws, size_t ws_size,
                              hipStream_t stream) {
  const float* x    = (const float*)d_in[0];
  const float* w    = (const float*)d_in[1];
  const float* bias = (const float*)d_in[2];
  float* out  = (float*)d_out;
  float* outM = out + (size_t)B_ * C_ * S_;
  float* acc  = (float*)d_ws;                       // [B,S,HW] = 1.6 MB
  float* wT   = acc + (size_t)B_ * S_ * HW_;        // [C][72]  = 221 KB

  hipMemsetAsync(acc, 0, (size_t)B_ * S_ * HW_ * sizeof(float), stream);
  wtrans_k<<<(C_ * 72) / 256, 256, 0, stream>>>(w, wT);
  conv_k<<<dim3(B_, NCHUNK_), 256, 0, stream>>>(x, wT, acc);
  mask_bias_k<<<(B_ * S_ * HW_ / 4 + 255) / 256, 256, 0, stream>>>(acc, bias, outM);
  einsum_k<<<dim3(12, B_), 256, 0, stream>>>(x, acc, bias, out);
}

// Round 8
// 344.441 us; speedup vs baseline: 1.4765x; 1.0833x over previous
//
#include <hip/hip_runtime.h>

#define B_ 64
#define C_ 768
#define S_ 8
#define HW_ 784
// conv
#define CPB_ 48               // channels per conv block
#define NCHUNK_ 16            // C / CPB
#define CSTEP_ 4              // channels staged per step
#define NSTEP_ 12             // CPB / CSTEP
#define ROWS_ 16              // 14 output rows + 2 halo rows
#define FW_ 30                // frame width (28 + 2 halo cols)
#define FRH_ (ROWS_ * FW_)    // 480 dwords per channel frame

// ---------------- K0: weight transpose wT[c][s*9+t] = w[s][c][t] -------------
__global__ __launch_bounds__(256) void wtrans_k(
    const float* __restrict__ w, float* __restrict__ wT)
{
  int idx = blockIdx.x * 256 + threadIdx.x;     // < 768*72 = 55296
  int c = idx / 72, r = idx - c * 72;
  int s = r / 9,  t = r - s * 9;
  wT[idx] = w[(size_t)s * (C_ * 9) + c * 9 + t];
}

// ---------------- K1: conv partials (2-px threads, hw-halved grid) -----------
// grid (64, 16, 2), block 256 (196 active). 8 blocks/CU target.
__global__ __launch_bounds__(256) void conv_k(
    const float* __restrict__ x, const float* __restrict__ wT,
    float* __restrict__ mask_acc)
{
  __shared__ float xb[CSTEP_ * FRH_];   // 7680 B
  const int tid = threadIdx.x;
  const int b   = blockIdx.x;
  const int c0  = blockIdx.y * CPB_;
  const int h0  = blockIdx.z * 14;      // output-row base of this half
  const bool act = tid < 196;
  const int duo = act ? tid : 0;
  const int hl  = duo / 14;             // 0..13 local row
  const int w2  = (duo - hl * 14) * 2;  // 0,2,..,26 col base
  const int pb  = (hl + 1) * FW_ + (w2 + 1);

  // zero once: halo rows/cols persist, interior rewritten every step
  for (int i = tid; i < CSTEP_ * FRH_; i += 256) xb[i] = 0.0f;

  const float4* src4 = (const float4*)(x + ((size_t)b * C_ + c0) * HW_);

  float acc[2][S_];
  #pragma unroll
  for (int px = 0; px < 2; ++px)
    #pragma unroll
    for (int s = 0; s < S_; ++s) acc[px][s] = 0.0f;

  for (int k = 0; k < NSTEP_; ++k) {
    __syncthreads();                    // zero-init / prev-step reads done
    #pragma unroll
    for (int r = 0; r < 2; ++r) {
      int i4 = tid + r * 256;
      if (i4 < CSTEP_ * ROWS_ * 7) {    // 448 float4
        int cl = i4 / 112, rr = i4 - cl * 112;
        int fr = rr / 7, c4 = rr - fr * 7;
        int gr = h0 - 1 + fr;           // global row
        if (gr >= 0 && gr < 28) {
          float4 v = src4[(k * CSTEP_ + cl) * 196 + gr * 7 + c4];
          float* d = &xb[cl * FRH_ + fr * FW_ + c4 * 4 + 1];
          d[0] = v.x; d[1] = v.y; d[2] = v.z; d[3] = v.w;
        }
      }
    }
    __syncthreads();                    // tile visible

    if (act) {
      #pragma unroll
      for (int cl = 0; cl < CSTEP_; ++cl) {
        const float* f = &xb[cl * FRH_ + pb];
        float xv[3][4];                 // 3 tap-rows x 4 cols covers 2 px
        #pragma unroll
        for (int r3 = 0; r3 < 3; ++r3)
          #pragma unroll
          for (int m = 0; m < 4; ++m)
            xv[r3][m] = f[(r3 - 1) * FW_ - 1 + m];

        const float4* wrow = (const float4*)(wT + (size_t)(c0 + k * CSTEP_ + cl) * 72);
        float wa[36];
        #pragma unroll
        for (int i = 0; i < 9; ++i) ((float4*)wa)[i] = wrow[i];       // s=0..3
        #pragma unroll
        for (int s = 0; s < 4; ++s)
          #pragma unroll
          for (int px = 0; px < 2; ++px) {
            float a = acc[px][s];
            #pragma unroll
            for (int r3 = 0; r3 < 3; ++r3)
              #pragma unroll
              for (int kx = 0; kx < 3; ++kx)
                a = fmaf(xv[r3][px + kx], wa[s * 9 + r3 * 3 + kx], a);
            acc[px][s] = a;
          }
        #pragma unroll
        for (int i = 0; i < 9; ++i) ((float4*)wa)[i] = wrow[9 + i];   // s=4..7
        #pragma unroll
        for (int s = 0; s < 4; ++s)
          #pragma unroll
          for (int px = 0; px < 2; ++px) {
            float a = acc[px][s + 4];
            #pragma unroll
            for (int r3 = 0; r3 < 3; ++r3)
              #pragma unroll
              for (int kx = 0; kx < 3; ++kx)
                a = fmaf(xv[r3][px + kx], wa[s * 9 + r3 * 3 + kx], a);
            acc[px][s + 4] = a;
          }
      }
    }
  }

  if (act) {
    float* dst = mask_acc + (size_t)b * S_ * HW_ + (h0 + hl) * 28 + w2;
    #pragma unroll
    for (int s = 0; s < S_; ++s)
      #pragma unroll
      for (int px = 0; px < 2; ++px)
        atomicAdd(dst + (size_t)s * HW_ + px, acc[px][s]);
  }
}

// ---------------- K2: region_mask output = mask_acc + bias -------------------
__global__ __launch_bounds__(256) void mask_bias_k(
    const float* __restrict__ mask_acc, const float* __restrict__ bias,
    float* __restrict__ outM)
{
  int i4 = blockIdx.x * 256 + threadIdx.x;        // < 100352
  float4 v = ((const float4*)mask_acc)[i4];
  int s = (i4 / 196) & 7;
  float bv = bias[s];
  v.x += bv; v.y += bv; v.z += bv; v.w += bv;
  ((float4*)outM)[i4] = v;
}

// ---------------- K3: learned = (x . m_raw + bias * sum(x)) / HW -------------
// grid (12, 64), block 256. Both operands in LDS (pure in-order DS waits).
// x tile XOR-swizzled: slot = jf ^ (c&15) -> b128 reads at 2-sweep minimum.
__global__ __launch_bounds__(256) void einsum_k(
    const float* __restrict__ x, const float* __restrict__ mask_acc,
    const float* __restrict__ bias, float* __restrict__ out)
{
  __shared__ float xs[64 * 128];        // 32768 B: 64 ch x 32 f4-slots
  __shared__ float ms[8 * 112];         // 3584 B: mask chunk
  const int tid = threadIdx.x;
  const int cx  = blockIdx.x;
  const int b   = blockIdx.y;
  const int c0  = cx * 64;
  const int q   = tid >> 6;             // wave -> jf phase (0..3)
  const int cl  = tid & 63;             // channel lane

  float acc[S_];
  #pragma unroll
  for (int s = 0; s < S_; ++s) acc[s] = 0.0f;
  float sumx = 0.0f;

  const float4* src4 = (const float4*)(x + ((size_t)b * C_ + c0) * HW_);
  const float*  mrow = mask_acc + (size_t)b * S_ * HW_;

  for (int rnd = 0; rnd < 7; ++rnd) {
    __syncthreads();                    // previous round's reads done
    #pragma unroll
    for (int r = 0; r < 7; ++r) {
      int i4 = tid + r * 256;           // exactly 1792 = 7*256
      int c = i4 / 28, jf = i4 - c * 28;
      float4 v = src4[c * 196 + rnd * 28 + jf];
      *(float4*)&xs[c * 128 + (jf ^ (c & 15)) * 4] = v;
    }
    if (tid < 224) {                    // 8 s-rows x 28 f4
      int s = tid / 28, jf = tid - s * 28;
      float4 v = *(const float4*)(mrow + (size_t)s * HW_ + rnd * 112 + jf * 4);
      *(float4*)&ms[s * 112 + jf * 4] = v;
    }
    __syncthreads();

    #pragma unroll
    for (int t = 0; t < 7; ++t) {
      const int jf = q + t * 4;         // this wave's f4 column
      float4 xa = *(const float4*)&xs[cl * 128 + (jf ^ (cl & 15)) * 4];
      sumx += xa.x + xa.y + xa.z + xa.w;
      #pragma unroll
      for (int s = 0; s < S_; ++s) {
        float4 m = *(const float4*)&ms[s * 112 + jf * 4];  // uniform broadcast
        float a = acc[s];
        a = fmaf(xa.x, m.x, a); a = fmaf(xa.y, m.y, a);
        a = fmaf(xa.z, m.z, a); a = fmaf(xa.w, m.w, a);
        acc[s] = a;
      }
    }
  }

  // reduce 4 waves through LDS (reuse xs)
  __syncthreads();
  float* red = xs;                      // 256*9 floats
  #pragma unroll
  for (int s = 0; s < S_; ++s) red[tid * 9 + s] = acc[s];
  red[tid * 9 + 8] = sumx;
  __syncthreads();

  for (int i = tid; i < 64 * S_; i += 256) {
    int c = i >> 3, s = i & 7;
    float vs = 0.0f, vx = 0.0f;
    #pragma unroll
    for (int qq = 0; qq < 4; ++qq) {
      vs += red[(qq * 64 + c) * 9 + s];
      vx += red[(qq * 64 + c) * 9 + 8];
    }
    out[((size_t)b * C_ + c0 + c) * S_ + s] = (vs + bias[s] * vx) * (1.0f / HW_);
  }
}

extern "C" void kernel_launch(void* const* d_in, const int* in_sizes, int n_in,
                              void* d_out, int out_size, void* d_ws, size_t ws_size,
                              hipStream_t stream) {
  const float* x    = (const float*)d_in[0];
  const float* w    = (const float*)d_in[1];
  const float* bias = (const float*)d_in[2];
  float* out  = (float*)d_out;
  float* outM = out + (size_t)B_ * C_ * S_;
  float* acc  = (float*)d_ws;                       // [B,S,HW] = 1.6 MB
  float* wT   = acc + (size_t)B_ * S_ * HW_;        // [C][72]  = 221 KB

  hipMemsetAsync(acc, 0, (size_t)B_ * S_ * HW_ * sizeof(float), stream);
  wtrans_k<<<(C_ * 72) / 256, 256, 0, stream>>>(w, wT);
  conv_k<<<dim3(B_, NCHUNK_, 2), 256, 0, stream>>>(x, wT, acc);
  mask_bias_k<<<(B_ * S_ * HW_ / 4 + 255) / 256, 256, 0, stream>>>(acc, bias, outM);
  einsum_k<<<dim3(12, B_), 256, 0, stream>>>(x, acc, bias, out);
}

// Round 9
// 334.593 us; speedup vs baseline: 1.5199x; 1.0294x over previous
//
#include <hip/hip_runtime.h>

#define B_ 64
#define C_ 768
#define S_ 8
#define HW_ 784
#define CPB_ 48               // channels per conv block
#define NCHUNK_ 16            // C / CPB

// ---------------- K0: weight transpose wT2[c][t][s] = w[s][c][t] -------------
__global__ __launch_bounds__(256) void wtrans_k(
    const float* __restrict__ w, float* __restrict__ wT2)
{
  int idx = blockIdx.x * 256 + threadIdx.x;     // < 768*72 = 55296
  int c = idx / 72, r = idx - c * 72;
  int t = r / 8, s = r - t * 8;
  wT2[idx] = w[(size_t)s * (C_ * 9) + c * 9 + t];
}

// ---------------- K1: conv partials ------------------------------------------
// grid (98, 16), block 256 = 25088 threads = 64 b x 392 vertical px-pairs.
// Weights in LDS (uniform ds_read_b128 broadcast); taps direct from global
// (L1/L2-hot, coalesced); NO per-step barriers, NO SMEM in hot loop.
__global__ __launch_bounds__(256) void conv_k(
    const float* __restrict__ x, const float* __restrict__ wT2,
    float* __restrict__ mask_acc)
{
  __shared__ float wl[CPB_ * 72];   // 13824 B, [cl][t][8s]
  const int tid = threadIdx.x;
  const int c0  = blockIdx.y * CPB_;

  {
    const float4* wsrc = (const float4*)(wT2 + (size_t)c0 * 72);
    float4* wd = (float4*)wl;
    #pragma unroll
    for (int r = 0; r < 4; ++r) {
      int i = tid + r * 256;
      if (i < CPB_ * 18) wd[i] = wsrc[i];
    }
  }
  __syncthreads();                   // the only barrier

  const int flat = blockIdx.x * 256 + tid;   // < 25088
  const int b    = flat / 392;
  const int pr   = flat - b * 392;
  const int h2   = pr / 28;          // 0..13
  const int wI   = pr - h2 * 28;     // 0..27
  const int h    = h2 * 2;           // top row of vertical pair

  // tap geometry: rows h-1..h+2 (4), cols w-1..w+1 (3); clamp + 0/1 mask
  int ro[4]; float rm[4];
  #pragma unroll
  for (int dr = 0; dr < 4; ++dr) {
    int r = h - 1 + dr;
    rm[dr] = (r >= 0 && r < 28) ? 1.0f : 0.0f;
    ro[dr] = min(max(r, 0), 27) * 28;
  }
  int co[3]; float cm[3];
  #pragma unroll
  for (int dc = 0; dc < 3; ++dc) {
    int cc = wI - 1 + dc;
    cm[dc] = (cc >= 0 && cc < 28) ? 1.0f : 0.0f;
    co[dc] = min(max(cc, 0), 27);
  }
  int   eoff[12]; float msk[12];
  #pragma unroll
  for (int dr = 0; dr < 4; ++dr)
    #pragma unroll
    for (int dc = 0; dc < 3; ++dc) {
      eoff[dr * 3 + dc] = ro[dr] + co[dc];
      msk[dr * 3 + dc]  = rm[dr] * cm[dc];
    }

  float acc[2][S_];
  #pragma unroll
  for (int px = 0; px < 2; ++px)
    #pragma unroll
    for (int s = 0; s < S_; ++s) acc[px][s] = 0.0f;

  int xoff = (b * C_ + c0) * HW_;    // element index, fits int32

  for (int cl = 0; cl < CPB_; ++cl, xoff += HW_) {
    float xv[12];
    #pragma unroll
    for (int t = 0; t < 12; ++t)
      xv[t] = x[xoff + eoff[t]] * msk[t];   // coalesced, L1/L2-hot

    const float4* wrow = (const float4*)&wl[cl * 72];
    #pragma unroll
    for (int ky = 0; ky < 3; ++ky)
      #pragma unroll
      for (int kx = 0; kx < 3; ++kx) {
        const int t9 = ky * 3 + kx;
        float4 wa = wrow[t9 * 2];       // s0..3, uniform broadcast
        float4 wb = wrow[t9 * 2 + 1];   // s4..7
        float x0 = xv[ky * 3 + kx];           // pixel (h, w)
        float x1 = xv[(ky + 1) * 3 + kx];     // pixel (h+1, w)
        acc[0][0] = fmaf(x0, wa.x, acc[0][0]);
        acc[0][1] = fmaf(x0, wa.y, acc[0][1]);
        acc[0][2] = fmaf(x0, wa.z, acc[0][2]);
        acc[0][3] = fmaf(x0, wa.w, acc[0][3]);
        acc[0][4] = fmaf(x0, wb.x, acc[0][4]);
        acc[0][5] = fmaf(x0, wb.y, acc[0][5]);
        acc[0][6] = fmaf(x0, wb.z, acc[0][6]);
        acc[0][7] = fmaf(x0, wb.w, acc[0][7]);
        acc[1][0] = fmaf(x1, wa.x, acc[1][0]);
        acc[1][1] = fmaf(x1, wa.y, acc[1][1]);
        acc[1][2] = fmaf(x1, wa.z, acc[1][2]);
        acc[1][3] = fmaf(x1, wa.w, acc[1][3]);
        acc[1][4] = fmaf(x1, wb.x, acc[1][4]);
        acc[1][5] = fmaf(x1, wb.y, acc[1][5]);
        acc[1][6] = fmaf(x1, wb.z, acc[1][6]);
        acc[1][7] = fmaf(x1, wb.w, acc[1][7]);
      }
  }

  float* dst = mask_acc + (size_t)b * S_ * HW_ + h * 28 + wI;
  #pragma unroll
  for (int s = 0; s < S_; ++s)
    #pragma unroll
    for (int px = 0; px < 2; ++px)
      atomicAdd(dst + (size_t)s * HW_ + px * 28, acc[px][s]);
}

// ---------------- K2: region_mask output = mask_acc + bias -------------------
__global__ __launch_bounds__(256) void mask_bias_k(
    const float* __restrict__ mask_acc, const float* __restrict__ bias,
    float* __restrict__ outM)
{
  int i4 = blockIdx.x * 256 + threadIdx.x;        // < 100352
  float4 v = ((const float4*)mask_acc)[i4];
  int s = (i4 / 196) & 7;
  float bv = bias[s];
  v.x += bv; v.y += bv; v.z += bv; v.w += bv;
  ((float4*)outM)[i4] = v;
}

// ---------------- K3: learned = (x.m_raw + bias*sum(x)) / HW -----------------
// grid (96, 64), block 256. Wave owns 2 channel rows; LDS-free, barrier-free.
// x: coalesced f4 stream (HBM); mask: coalesced f4, L2-resident (1.6 MB).
__global__ __launch_bounds__(256) void einsum_k(
    const float* __restrict__ x, const float* __restrict__ mask_acc,
    const float* __restrict__ bias, float* __restrict__ out)
{
  const int tid  = threadIdx.x;
  const int lane = tid & 63;
  const int wv   = tid >> 6;
  const int b    = blockIdx.y;
  const int c    = (blockIdx.x * 4 + wv) * 2;    // channel pair base

  const float4* xr0 = (const float4*)(x + ((size_t)b * C_ + c) * HW_);
  const float4* xr1 = xr0 + 196;
  const float4* mr  = (const float4*)(mask_acc + (size_t)b * S_ * HW_);

  float a0[S_], a1[S_];
  #pragma unroll
  for (int s = 0; s < S_; ++s) { a0[s] = 0.0f; a1[s] = 0.0f; }
  float sx0 = 0.0f, sx1 = 0.0f;

  #pragma unroll
  for (int jf = 0; jf < 3; ++jf) {
    int j4 = jf * 64 + lane;                 // 0..191, always valid
    float4 xa = xr0[j4];
    float4 xb = xr1[j4];
    sx0 += xa.x + xa.y + xa.z + xa.w;
    sx1 += xb.x + xb.y + xb.z + xb.w;
    #pragma unroll
    for (int s = 0; s < S_; ++s) {
      float4 m = mr[s * 196 + j4];
      a0[s] = fmaf(xa.x, m.x, fmaf(xa.y, m.y, fmaf(xa.z, m.z, fmaf(xa.w, m.w, a0[s]))));
      a1[s] = fmaf(xb.x, m.x, fmaf(xb.y, m.y, fmaf(xb.z, m.z, fmaf(xb.w, m.w, a1[s]))));
    }
  }
  if (lane < 4) {                            // tail: j4 = 192..195
    int j4 = 192 + lane;
    float4 xa = xr0[j4];
    float4 xb = xr1[j4];
    sx0 += xa.x + xa.y + xa.z + xa.w;
    sx1 += xb.x + xb.y + xb.z + xb.w;
    #pragma unroll
    for (int s = 0; s < S_; ++s) {
      float4 m = mr[s * 196 + j4];
      a0[s] = fmaf(xa.x, m.x, fmaf(xa.y, m.y, fmaf(xa.z, m.z, fmaf(xa.w, m.w, a0[s]))));
      a1[s] = fmaf(xb.x, m.x, fmaf(xb.y, m.y, fmaf(xb.z, m.z, fmaf(xb.w, m.w, a1[s]))));
    }
  }

  // butterfly reduce 18 values across the wave
  #pragma unroll
  for (int d = 1; d < 64; d <<= 1) {
    #pragma unroll
    for (int s = 0; s < S_; ++s) {
      a0[s] += __shfl_xor(a0[s], d, 64);
      a1[s] += __shfl_xor(a1[s], d, 64);
    }
    sx0 += __shfl_xor(sx0, d, 64);
    sx1 += __shfl_xor(sx1, d, 64);
  }

  if (lane == 0) {
    float* o = out + ((size_t)b * C_ + c) * S_;
    #pragma unroll
    for (int s = 0; s < S_; ++s) {
      o[s]      = (a0[s] + bias[s] * sx0) * (1.0f / HW_);
      o[S_ + s] = (a1[s] + bias[s] * sx1) * (1.0f / HW_);
    }
  }
}

extern "C" void kernel_launch(void* const* d_in, const int* in_sizes, int n_in,
                              void* d_out, int out_size, void* d_ws, size_t ws_size,
                              hipStream_t stream) {
  const float* x    = (const float*)d_in[0];
  const float* w    = (const float*)d_in[1];
  const float* bias = (const float*)d_in[2];
  float* out  = (float*)d_out;
  float* outM = out + (size_t)B_ * C_ * S_;
  float* acc  = (float*)d_ws;                       // [B,S,HW] = 1.6 MB
  float* wT2  = acc + (size_t)B_ * S_ * HW_;        // [C][9][8] = 221 KB

  hipMemsetAsync(acc, 0, (size_t)B_ * S_ * HW_ * sizeof(float), stream);
  wtrans_k<<<(C_ * 72) / 256, 256, 0, stream>>>(w, wT2);
  conv_k<<<dim3(98, NCHUNK_), 256, 0, stream>>>(x, wT2, acc);
  mask_bias_k<<<(B_ * S_ * HW_ / 4 + 255) / 256, 256, 0, stream>>>(acc, bias, outM);
  einsum_k<<<dim3(96, B_), 256, 0, stream>>>(x, acc, bias, out);
}

// Round 11
// 295.151 us; speedup vs baseline: 1.7230x; 1.1336x over previous
//
#include <hip/hip_runtime.h>

typedef __attribute__((ext_vector_type(8))) short short8;
typedef __attribute__((ext_vector_type(4))) float f32x4;

#define B_ 64
#define C_ 768
#define S_ 8
#define HW_ 784
// conv geometry
#define NQ_ 4            // image quarters: 7 output rows each
#define KSPLIT_ 3        // channel splits (grid.z)
#define KCH_ 256         // channels per block
#define NKS_ 8           // K-steps per block (KCH_/32)
#define PP_ 330          // frame positions: 11 rows x 30 cols (rows 9,10 = zero guard)
#define FS_ 40           // ushorts per position: 32ch*2B + 16B pad = 80B (16B-aligned, banks spread)

// ---- K0: wpack[t][col][c]: col<8 -> bf16_hi(w[s=col][c][t]); col>=8 -> bf16 residual ----
__global__ __launch_bounds__(256) void wtrans_k(
    const float* __restrict__ w, unsigned short* __restrict__ wpack)
{
  int idx = blockIdx.x * 256 + threadIdx.x;      // < 9*16*768 = 110592
  int c   = idx % C_;
  int col = (idx / C_) & 15;
  int t   = idx / (C_ * 16);
  int s   = col & 7;
  float wv = w[(size_t)s * (C_ * 9) + c * 9 + t];
  unsigned u = __builtin_bit_cast(unsigned, wv);
  unsigned short hi = (unsigned short)(u >> 16);
  float r = wv - __builtin_bit_cast(float, u & 0xffff0000u);
  unsigned short lo = (unsigned short)(__builtin_bit_cast(unsigned, r) >> 16);
  wpack[idx] = (col < 8) ? hi : lo;
}

// ---- K1: MFMA conv. Per-tap GEMM: out[p,s] += xT[p+delta, c] * w[c,t,s] ----
// grid (64 b, 4 quarters, 3 ksplit), block 256 (4 waves). LDS 52.8KB -> 3 blocks/CU.
__global__ __launch_bounds__(256) void conv_k(
    const float* __restrict__ x, const unsigned short* __restrict__ wpack,
    float* __restrict__ mask_acc)
{
  __shared__ unsigned short fh[PP_ * FS_];   // 26400 B: bf16-hi, [pos][32ch]
  __shared__ unsigned short fl[PP_ * FS_];   // 26400 B: bf16-lo
  const int tid  = threadIdx.x;
  const int lane = tid & 63;
  const int wv   = tid >> 6;
  const int b    = blockIdx.x;
  const int q    = blockIdx.y;
  const int cz   = blockIdx.z * KCH_;
  const int col  = lane & 15;     // MFMA col (s for <8, s-lo for >=8)
  const int cg   = lane >> 4;     // k-group

  // zero frames once: borders + guard rows persist; interior rewritten per K-step
  for (int i = tid; i < PP_ * FS_ / 2; i += 256) {
    ((unsigned*)fh)[i] = 0u; ((unsigned*)fl)[i] = 0u;
  }

  // per-lane A-row geometry for owned tiles (13 tiles of 16 px over 196+12 garbage)
  int ppt[4], tb[4], ntile = 0;
  #pragma unroll
  for (int i = 0; i < 4; ++i) {
    int tl = wv + i * 4;
    if (tl < 13) {
      int pl = tl * 16 + col;               // A-frag row = lane&15
      int h = pl / 28, wc = pl - h * 28;
      ppt[i] = (h + 1) * 30 + wc + 1;
      tb[i]  = tl * 16;
      ntile  = i + 1;
    }
  }

  f32x4 acc[4];
  #pragma unroll
  for (int i = 0; i < 4; ++i) acc[i] = (f32x4){0.f, 0.f, 0.f, 0.f};

  for (int ks = 0; ks < NKS_; ++ks) {
    const int c0 = cz + ks * 32;
    __syncthreads();                         // prior compute done before overwrite
    // stage 32ch x 9 rows x 28 cols, transposed, hi/lo split
    #pragma unroll
    for (int it = 0; it < 4; ++it) {
      int i = tid + it * 256;
      if (i < 1008) {                        // 16 ch-pairs x 9 rows x 7 f4
        int cp = i / 63, rem = i - cp * 63;
        int r = rem / 7, c4 = rem - r * 7;
        int gr = q * 7 - 1 + r;
        if (gr >= 0 && gr < 28) {
          float4 va = ((const float4*)x)[(size_t)(b * C_ + c0 + 2 * cp) * 196 + gr * 7 + c4];
          float4 vb = ((const float4*)x)[(size_t)(b * C_ + c0 + 2 * cp + 1) * 196 + gr * 7 + c4];
          #pragma unroll
          for (int j = 0; j < 4; ++j) {
            int pp = r * 30 + c4 * 4 + j + 1;
            float a = ((const float*)&va)[j], bb = ((const float*)&vb)[j];
            unsigned ua = __builtin_bit_cast(unsigned, a);
            unsigned ub = __builtin_bit_cast(unsigned, bb);
            float ra = a  - __builtin_bit_cast(float, ua & 0xffff0000u);
            float rb = bb - __builtin_bit_cast(float, ub & 0xffff0000u);
            unsigned la = __builtin_bit_cast(unsigned, ra) >> 16;
            unsigned lb = __builtin_bit_cast(unsigned, rb) >> 16;
            ((unsigned*)fh)[pp * 20 + cp] = (ua >> 16) | ((ub >> 16) << 16);
            ((unsigned*)fl)[pp * 20 + cp] = la | (lb << 16);
          }
        }
      }
    }
    // B-frags for 9 taps: lane reads 8 consecutive ch at (t, col) — 16B, L2-resident
    short8 bf[9];
    #pragma unroll
    for (int t = 0; t < 9; ++t)
      bf[t] = *(const short8*)(wpack + (size_t)(t * 16 + col) * C_ + c0 + cg * 8);
    __syncthreads();                         // tile visible

    #pragma unroll
    for (int i = 0; i < 4; ++i) {
      if (i < ntile) {
        const int base = ppt[i] * FS_ + cg * 8;
        #pragma unroll
        for (int dy = -1; dy <= 1; ++dy)
          #pragma unroll
          for (int dx = -1; dx <= 1; ++dx) {
            int off = base + (dy * 30 + dx) * FS_;
            short8 ah = *(const short8*)(fh + off);
            short8 al = *(const short8*)(fl + off);
            int t = (dy + 1) * 3 + (dx + 1);
            acc[i] = __builtin_amdgcn_mfma_f32_16x16x32_bf16(ah, bf[t], acc[i], 0, 0, 0);
            acc[i] = __builtin_amdgcn_mfma_f32_16x16x32_bf16(al, bf[t], acc[i], 0, 0, 0);
          }
      }
    }
  }

  // epilogue: D layout col=lane&15, row=(lane>>4)*4+reg; out = D[:,s] + D[:,s+8]
  #pragma unroll
  for (int i = 0; i < 4; ++i) {
    if (i < ntile) {
      #pragma unroll
      for (int r4 = 0; r4 < 4; ++r4) {
        float v = acc[i][r4];
        v += __shfl_xor(v, 8, 64);           // add the wl-column partner
        int pl = tb[i] + cg * 4 + r4;        // pixel within quarter
        if (col < 8 && pl < 196)
          atomicAdd(mask_acc + ((size_t)b * S_ + col) * HW_ + q * 196 + pl, v);
      }
    }
  }
}

// ---- K2: region_mask output = mask_acc + bias ----
__global__ __launch_bounds__(256) void mask_bias_k(
    const float* __restrict__ mask_acc, const float* __restrict__ bias,
    float* __restrict__ outM)
{
  int i4 = blockIdx.x * 256 + threadIdx.x;        // < 100352
  float4 v = ((const float4*)mask_acc)[i4];
  int s = (i4 / 196) & 7;
  float bv = bias[s];
  v.x += bv; v.y += bv; v.z += bv; v.w += bv;
  ((float4*)outM)[i4] = v;
}

// ---- K3: learned = (x.m_raw + bias*sum(x)) / HW ---- (unchanged from r9)
__global__ __launch_bounds__(256) void einsum_k(
    const float* __restrict__ x, const float* __restrict__ mask_acc,
    const float* __restrict__ bias, float* __restrict__ out)
{
  const int tid  = threadIdx.x;
  const int lane = tid & 63;
  const int wv   = tid >> 6;
  const int b    = blockIdx.y;
  const int c    = (blockIdx.x * 4 + wv) * 2;

  const float4* xr0 = (const float4*)(x + ((size_t)b * C_ + c) * HW_);
  const float4* xr1 = xr0 + 196;
  const float4* mr  = (const float4*)(mask_acc + (size_t)b * S_ * HW_);

  float a0[S_], a1[S_];
  #pragma unroll
  for (int s = 0; s < S_; ++s) { a0[s] = 0.0f; a1[s] = 0.0f; }
  float sx0 = 0.0f, sx1 = 0.0f;

  #pragma unroll
  for (int jf = 0; jf < 3; ++jf) {
    int j4 = jf * 64 + lane;
    float4 xa = xr0[j4];
    float4 xb = xr1[j4];
    sx0 += xa.x + xa.y + xa.z + xa.w;
    sx1 += xb.x + xb.y + xb.z + xb.w;
    #pragma unroll
    for (int s = 0; s < S_; ++s) {
      float4 m = mr[s * 196 + j4];
      a0[s] = fmaf(xa.x, m.x, fmaf(xa.y, m.y, fmaf(xa.z, m.z, fmaf(xa.w, m.w, a0[s]))));
      a1[s] = fmaf(xb.x, m.x, fmaf(xb.y, m.y, fmaf(xb.z, m.z, fmaf(xb.w, m.w, a1[s]))));
    }
  }
  if (lane < 4) {
    int j4 = 192 + lane;
    float4 xa = xr0[j4];
    float4 xb = xr1[j4];
    sx0 += xa.x + xa.y + xa.z + xa.w;
    sx1 += xb.x + xb.y + xb.z + xb.w;
    #pragma unroll
    for (int s = 0; s < S_; ++s) {
      float4 m = mr[s * 196 + j4];
      a0[s] = fmaf(xa.x, m.x, fmaf(xa.y, m.y, fmaf(xa.z, m.z, fmaf(xa.w, m.w, a0[s]))));
      a1[s] = fmaf(xb.x, m.x, fmaf(xb.y, m.y, fmaf(xb.z, m.z, fmaf(xb.w, m.w, a1[s]))));
    }
  }

  #pragma unroll
  for (int d = 1; d < 64; d <<= 1) {
    #pragma unroll
    for (int s = 0; s < S_; ++s) {
      a0[s] += __shfl_xor(a0[s], d, 64);
      a1[s] += __shfl_xor(a1[s], d, 64);
    }
    sx0 += __shfl_xor(sx0, d, 64);
    sx1 += __shfl_xor(sx1, d, 64);
  }

  if (lane == 0) {
    float* o = out + ((size_t)b * C_ + c) * S_;
    #pragma unroll
    for (int s = 0; s < S_; ++s) {
      o[s]      = (a0[s] + bias[s] * sx0) * (1.0f / HW_);
      o[S_ + s] = (a1[s] + bias[s] * sx1) * (1.0f / HW_);
    }
  }
}

extern "C" void kernel_launch(void* const* d_in, const int* in_sizes, int n_in,
                              void* d_out, int out_size, void* d_ws, size_t ws_size,
                              hipStream_t stream) {
  const float* x    = (const float*)d_in[0];
  const float* w    = (const float*)d_in[1];
  const float* bias = (const float*)d_in[2];
  float* out  = (float*)d_out;
  float* outM = out + (size_t)B_ * C_ * S_;
  float* acc  = (float*)d_ws;                              // [B,S,HW] f32 = 1.6 MB
  unsigned short* wpack = (unsigned short*)(acc + (size_t)B_ * S_ * HW_);  // 216 KB

  hipMemsetAsync(acc, 0, (size_t)B_ * S_ * HW_ * sizeof(float), stream);
  wtrans_k<<<(9 * 16 * C_) / 256, 256, 0, stream>>>(w, wpack);
  conv_k<<<dim3(B_, NQ_, KSPLIT_), 256, 0, stream>>>(x, wpack, acc);
  mask_bias_k<<<(B_ * S_ * HW_ / 4 + 255) / 256, 256, 0, stream>>>(acc, bias, outM);
  einsum_k<<<dim3(96, B_), 256, 0, stream>>>(x, acc, bias, out);
}